// Round 3
// baseline (81.993 us; speedup 1.0000x reference)
//
#include <hip/hip_runtime.h>

// ProtoLayer: out[t][q][w] = -sum_c (query[t][q][c] - mean_s support[t][w*S+s][c])^2
// T=4, WAY=16, SHOT=8, QUERY=256 (=> 4096 queries/t), C=256. fp32 in/out.
// support_target is unused by the reference (prototype = plain reshape-mean).
//
// Round-3 structure:
//   1) proto_kernel (16 blocks): proto[t][w][c] = mean over shots -> d_ws (64 KB).
//   2) dist_kernel (512 blocks x 64 thr = 1 wave): block = 32 queries x 16 ways,
//      thread = 2q x 4w register tile -> 6 ds_read_b128 per c4-step for 8 dots
//      (round-2 was 4 reads / 4 dots). DS pipe/CU: 12288 -> 9216 cyc (~3.8 us).
//      Single-wave blocks: __syncthreads is wave-local (no inter-wave stall).
//      Staging via global_load_lds width=16 (layout is uniform-base + lane*16).
//      PITCH=260 floats (16B-aligned rows); q rows {qp, qp+16} -> 2-way bank
//      aliasing (free per m136); proto reads broadcast 2-way; staging contiguous.

constexpr int T_    = 4;
constexpr int WAY   = 16;
constexpr int SHOT  = 8;
constexpr int C     = 256;
constexpr int WQ    = 4096;            // queries per t
constexpr int C4    = C / 4;           // 64 float4 per row
constexpr int PITCH = 260;             // floats; row stride 1040 B (16B-aligned)

__device__ __forceinline__ void g2lds16(const float4* g, float* lds) {
    __builtin_amdgcn_global_load_lds(
        (const __attribute__((address_space(1))) void*)g,
        (__attribute__((address_space(3))) void*)lds, 16, 0, 0);
}

// ---------------- Kernel 1: prototypes ----------------
// grid = 16 blocks (t*4 + quarter), 256 threads; each thread one float4 output.
__global__ __launch_bounds__(256) void proto_kernel(
    const float* __restrict__ support,   // (T, WAY*SHOT, C)
    float* __restrict__ proto)           // (T, WAY, C) in d_ws
{
    const int t       = blockIdx.x >> 2;
    const int quarter = blockIdx.x & 3;
    const int idx     = quarter * 256 + threadIdx.x;   // [0, WAY*C4) = [0,1024)
    const int w  = idx >> 6;                            // [0,16)
    const int c4 = idx & 63;                            // [0,64)

    const float4* row = (const float4*)(support + (size_t)t * (WAY * SHOT * C))
                        + (w * SHOT) * C4 + c4;
    float4 s = make_float4(0.f, 0.f, 0.f, 0.f);
    #pragma unroll
    for (int sh = 0; sh < SHOT; ++sh) {
        float4 v = row[sh * C4];
        s.x += v.x; s.y += v.y; s.z += v.z; s.w += v.w;
    }
    s.x *= 0.125f; s.y *= 0.125f; s.z *= 0.125f; s.w *= 0.125f;

    ((float4*)(proto + (size_t)t * (WAY * C)))[idx] = s;
}

// ---------------- Kernel 2: distances ----------------
// grid = 512 (t*128 + qtile), 64 threads. Thread = queries {qp, qp+16} x ways
// {wg..wg+3}. Epilogue: two float4 stores; wave covers contiguous 1 KB regions.
__global__ __launch_bounds__(64) void dist_kernel(
    const float* __restrict__ query,    // (T, WQ, C)
    const float* __restrict__ proto,    // (T, WAY, C)
    float* __restrict__ out)            // (T, WQ, WAY)
{
    __shared__ float ps[WAY * PITCH];   // 16.6 KB
    __shared__ float qs[32  * PITCH];   // 33.3 KB  (total ~50 KB -> up to 3 blk/CU)

    const int tid = threadIdx.x;
    const int t   = blockIdx.x >> 7;            // 128 blocks per t
    const int qb  = (blockIdx.x & 127) * 32;

    // ---- stage: async global->LDS, one row (64 float4) per instruction ----
    const float4* psrc = (const float4*)(proto + (size_t)t * (WAY * C));
    const float4* qsrc = (const float4*)(query + ((size_t)t * WQ + qb) * C);
    #pragma unroll
    for (int i = 0; i < WAY; ++i)
        g2lds16(psrc + i * C4 + tid, &ps[i * PITCH]);
    #pragma unroll
    for (int i = 0; i < 32; ++i)
        g2lds16(qsrc + i * C4 + tid, &qs[i * PITCH]);
    __syncthreads();                    // drains vmcnt; single wave -> cheap

    // ---- compute: thread = 2 queries x 4 ways ----
    const int qp = tid >> 2;            // [0,16)
    const int wg = (tid & 3) * 4;       // 0,4,8,12

    const float* q0 = &qs[qp * PITCH];
    const float* q1 = &qs[(qp + 16) * PITCH];
    const float* p0 = &ps[(wg + 0) * PITCH];
    const float* p1 = &ps[(wg + 1) * PITCH];
    const float* p2 = &ps[(wg + 2) * PITCH];
    const float* p3 = &ps[(wg + 3) * PITCH];

    float a0[4] = {0.f, 0.f, 0.f, 0.f};
    float a1[4] = {0.f, 0.f, 0.f, 0.f};

    #pragma unroll 8
    for (int c = 0; c < C; c += 4) {
        float4 qa = *(const float4*)(q0 + c);
        float4 qv = *(const float4*)(q1 + c);
        const float* pw[4] = {p0 + c, p1 + c, p2 + c, p3 + c};
        #pragma unroll
        for (int j = 0; j < 4; ++j) {
            float4 pv = *(const float4*)pw[j];
            float d;
            d = qa.x - pv.x; a0[j] += d * d;
            d = qa.y - pv.y; a0[j] += d * d;
            d = qa.z - pv.z; a0[j] += d * d;
            d = qa.w - pv.w; a0[j] += d * d;
            d = qv.x - pv.x; a1[j] += d * d;
            d = qv.y - pv.y; a1[j] += d * d;
            d = qv.z - pv.z; a1[j] += d * d;
            d = qv.w - pv.w; a1[j] += d * d;
        }
    }

    // ---- epilogue: float4 stores (ways wg..wg+3 contiguous) ----
    float* ob = out + (((size_t)t * WQ + qb + qp) * WAY + wg);
    *(float4*)ob              = make_float4(-a0[0], -a0[1], -a0[2], -a0[3]);
    *(float4*)(ob + 16 * WAY) = make_float4(-a1[0], -a1[1], -a1[2], -a1[3]);
}

extern "C" void kernel_launch(void* const* d_in, const int* in_sizes, int n_in,
                              void* d_out, int out_size, void* d_ws, size_t ws_size,
                              hipStream_t stream) {
    const float* query   = (const float*)d_in[0];
    const float* support = (const float*)d_in[1];
    // d_in[2] (support_target) unused: reference ignores labels (plain reshape-mean).
    float* out   = (float*)d_out;
    float* proto = (float*)d_ws;        // 4*16*256*4 = 64 KB scratch

    proto_kernel<<<dim3(T_ * 4), 256, 0, stream>>>(support, proto);
    dist_kernel <<<dim3(T_ * 128), 64, 0, stream>>>(query, proto, out);
}